// Round 1
// baseline (1583.783 us; speedup 1.0000x reference)
//
#include <hip/hip_runtime.h>
#include <math.h>

#define NB 1024

__device__ __forceinline__ float dot4f(float4 a, float4 b){
  return a.x*b.x + a.y*b.y + a.z*b.z + a.w*b.w;
}

// ---------------- Branch 1: siRNA, S=21, D=16, H=2 heads, L=4 layers ----------------
__global__ __launch_bounds__(256) void b1_kernel(
    const float* __restrict__ inp,  // [NB][21][640]
    const float* __restrict__ xw,   // [16][640]
    const float* __restrict__ xb,   // [16]
    const float* __restrict__ qw,   // [4][48][16]
    const float* __restrict__ qb,   // [4][48]
    const float* __restrict__ ow,   // [4][16][16]
    const float* __restrict__ ob,   // [4][16]
    const float* __restrict__ f1w,  // [4][2048][16]
    const float* __restrict__ f1b,  // [4][2048]
    const float* __restrict__ f2w,  // [4][16][2048]
    const float* __restrict__ f2b,  // [4][16]
    const float* __restrict__ g1w,  // [4][16]
    const float* __restrict__ b1w,  // [4][16]
    const float* __restrict__ g2w,  // [4][16]
    const float* __restrict__ b2w,  // [4][16]
    const float* __restrict__ ymw,  // [4][16]
    const float* __restrict__ ymb,  // [4]
    float* __restrict__ outp)       // [NB][84]
{
  const int S = 21, D = 16, NT = S * D;   // 336
  // padded strides: xs/xr 20, qkv 52, sc 23, stageh 132, w2c 132, qkvw 17, ows 20
  __shared__ __align__(16) float xs[21*20];
  __shared__ __align__(16) float xr[21*20];
  __shared__ __align__(16) float qkv[21*52];
  __shared__ __align__(16) float sc[2*21*23];
  __shared__ __align__(16) float stageh[21*132];
  __shared__ __align__(16) float w2c[16*132];
  __shared__ __align__(16) float qkvw[48*17];
  __shared__ __align__(16) float owsb[16*20];
  __shared__ float vqb[48];
  __shared__ float vob[16], vg1[16], vb1[16], vg2[16], vb2[16], vf2b[16];
  __shared__ float mu[21], rsd[21];

  const int tid = threadIdx.x;
  const int b   = blockIdx.x;
  const float* A = inp + (size_t)b * 21 * 640;

  // ---------------- input projection: x = A @ xw^T, chunked over 640 ----------------
  float pacc0 = 0.f, pacc1 = 0.f;
  for (int c = 0; c < 5; ++c) {           // 5 chunks of 128 columns
    for (int idx = tid; idx < 21*32; idx += 256) {
      int s = idx >> 5, q4 = idx & 31;
      *(float4*)(stageh + s*132 + q4*4) = *(const float4*)(A + s*640 + c*128 + q4*4);
    }
    for (int idx = tid; idx < 16*32; idx += 256) {
      int i = idx >> 5, q4 = idx & 31;
      *(float4*)(w2c + i*132 + q4*4) = *(const float4*)(xw + i*640 + c*128 + q4*4);
    }
    __syncthreads();
    {
      int r = 0;
      for (int idx = tid; idx < NT; idx += 256, ++r) {
        int s = idx >> 4, i = idx & 15;
        float acc = 0.f;
        #pragma unroll
        for (int q = 0; q < 128; q += 4)
          acc += dot4f(*(const float4*)(stageh + s*132 + q), *(const float4*)(w2c + i*132 + q));
        if (r == 0) pacc0 += acc; else pacc1 += acc;
      }
    }
    __syncthreads();
  }
  {
    const float lf = -logf(10000.0f) / (float)D;
    int r = 0;
    for (int idx = tid; idx < NT; idx += 256, ++r) {
      int s = idx >> 4, i = idx & 15;
      float freq = expf((float)((i >> 1) * 2) * lf);
      float pe = (i & 1) ? cosf((float)s * freq) : sinf((float)s * freq);
      xs[s*20 + i] = ((r == 0) ? pacc0 : pacc1) + xb[i] + pe;
    }
  }
  __syncthreads();

  // ---------------- 4 encoder layers ----------------
  for (int L = 0; L < 4; ++L) {
    const float* qwL  = qw  + L*48*16;
    const float* f1wL = f1w + (size_t)L*2048*16;
    const float* f1bL = f1b + L*2048;
    const float* f2wL = f2w + (size_t)L*16*2048;

    for (int idx = tid; idx < 48*16; idx += 256) { int e = idx >> 4, k = idx & 15; qkvw[e*17+k] = qwL[idx]; }
    if (tid < 48) vqb[tid] = qb[L*48 + tid];
    for (int idx = tid; idx < 256; idx += 256) { int i = idx >> 4, cc = idx & 15; owsb[i*20+cc] = ow[L*256 + idx]; }
    if (tid < 16) {
      vob[tid]  = ob[L*16+tid];  vg1[tid] = g1w[L*16+tid]; vb1[tid] = b1w[L*16+tid];
      vg2[tid]  = g2w[L*16+tid]; vb2[tid] = b2w[L*16+tid]; vf2b[tid] = f2b[L*16+tid];
    }
    __syncthreads();

    // qkv = x @ qkv_w^T + qkv_b  -> [21][48]
    for (int idx = tid; idx < 21*48; idx += 256) {
      int s = idx / 48, e = idx % 48;
      float a = vqb[e];
      #pragma unroll
      for (int k = 0; k < 16; ++k) a += xs[s*20+k] * qkvw[e*17+k];
      qkv[s*52 + e] = a;
    }
    __syncthreads();

    // scores: 2 heads, dh=8
    for (int idx = tid; idx < 2*21*21; idx += 256) {
      int h = idx / 441, r2 = idx % 441, i = r2 / 21, j = r2 % 21;
      float a = 0.f;
      #pragma unroll
      for (int c = 0; c < 8; ++c) a += qkv[i*52 + h*8 + c] * qkv[j*52 + 16 + h*8 + c];
      sc[(h*21 + i)*23 + j] = a * 0.35355339059327373f;   // 1/sqrt(8)
    }
    __syncthreads();

    // softmax per (head,row)
    for (int r = tid; r < 42; r += 256) {
      float* row = sc + r*23;
      float m = row[0];
      for (int j = 1; j < 21; ++j) m = fmaxf(m, row[j]);
      float ssum = 0.f;
      for (int j = 0; j < 21; ++j) { float e = __expf(row[j] - m); row[j] = e; ssum += e; }
      float inv = 1.f / ssum;
      for (int j = 0; j < 21; ++j) row[j] *= inv;
    }
    __syncthreads();

    // attn out: o[s][h*8+c] = sum_j att * v   -> stageh as o[21][.] stride 132
    for (int idx = tid; idx < NT; idx += 256) {
      int s = idx >> 4, cc = idx & 15;
      int h = cc >> 3, c = cc & 7;
      const float* row = sc + (h*21 + s)*23;
      float a = 0.f;
      for (int j = 0; j < 21; ++j) a += row[j] * qkv[j*52 + 32 + h*8 + c];
      stageh[s*132 + cc] = a;
    }
    __syncthreads();

    // out proj + residual -> xr
    for (int idx = tid; idx < NT; idx += 256) {
      int s = idx >> 4, i = idx & 15;
      float a = vob[i];
      #pragma unroll
      for (int c = 0; c < 16; ++c) a += stageh[s*132 + c] * owsb[i*20 + c];
      xr[s*20 + i] = xs[s*20 + i] + a;
    }
    __syncthreads();

    // LN1
    if (tid < 21) {
      float m = 0.f;
      #pragma unroll
      for (int k = 0; k < 16; ++k) m += xr[tid*20 + k];
      m *= (1.f/16.f);
      float v = 0.f;
      #pragma unroll
      for (int k = 0; k < 16; ++k) { float d = xr[tid*20 + k] - m; v += d*d; }
      v *= (1.f/16.f);
      mu[tid] = m; rsd[tid] = rsqrtf(v + 1e-5f);
    }
    __syncthreads();
    for (int idx = tid; idx < NT; idx += 256) {
      int s = idx >> 4, i = idx & 15;
      xs[s*20 + i] = (xr[s*20 + i] - mu[s]) * rsd[s] * vg1[i] + vb1[i];
    }
    __syncthreads();

    // FFN: 16 chunks of 128 ffn units
    float facc0 = 0.f, facc1 = 0.f;
    for (int ch = 0; ch < 16; ++ch) {
      for (int idx = tid; idx < 16*32; idx += 256) {
        int i = idx >> 5, q4 = idx & 31;
        *(float4*)(w2c + i*132 + q4*4) = *(const float4*)(f2wL + i*2048 + ch*128 + q4*4);
      }
      __syncthreads();
      { // phase A: h = relu(x @ f1w^T + b1)
        int jj = tid & 127, tg = tid >> 7;
        int gj = ch*128 + jj;
        float4 w0 = *(const float4*)(f1wL + (size_t)gj*16 + 0);
        float4 w1 = *(const float4*)(f1wL + (size_t)gj*16 + 4);
        float4 w2 = *(const float4*)(f1wL + (size_t)gj*16 + 8);
        float4 w3 = *(const float4*)(f1wL + (size_t)gj*16 + 12);
        float bb = f1bL[gj];
        for (int t = tg; t < 21; t += 2) {
          float4 x0 = *(const float4*)(xs + t*20 + 0);
          float4 x1 = *(const float4*)(xs + t*20 + 4);
          float4 x2 = *(const float4*)(xs + t*20 + 8);
          float4 x3 = *(const float4*)(xs + t*20 + 12);
          float a = bb + dot4f(x0,w0) + dot4f(x1,w1) + dot4f(x2,w2) + dot4f(x3,w3);
          stageh[t*132 + jj] = fmaxf(a, 0.f);
        }
      }
      __syncthreads();
      { // phase B: acc += h @ f2w^T
        int r = 0;
        for (int idx = tid; idx < NT; idx += 256, ++r) {
          int t = idx >> 4, i = idx & 15;
          float a = 0.f;
          #pragma unroll
          for (int q = 0; q < 128; q += 4)
            a += dot4f(*(const float4*)(stageh + t*132 + q), *(const float4*)(w2c + i*132 + q));
          if (r == 0) facc0 += a; else facc1 += a;
        }
      }
      __syncthreads();
    }
    { // residual + bias
      int r = 0;
      for (int idx = tid; idx < NT; idx += 256, ++r) {
        int t = idx >> 4, i = idx & 15;
        xr[t*20 + i] = xs[t*20 + i] + ((r == 0) ? facc0 : facc1) + vf2b[i];
      }
    }
    __syncthreads();
    // LN2
    if (tid < 21) {
      float m = 0.f;
      #pragma unroll
      for (int k = 0; k < 16; ++k) m += xr[tid*20 + k];
      m *= (1.f/16.f);
      float v = 0.f;
      #pragma unroll
      for (int k = 0; k < 16; ++k) { float d = xr[tid*20 + k] - m; v += d*d; }
      v *= (1.f/16.f);
      mu[tid] = m; rsd[tid] = rsqrtf(v + 1e-5f);
    }
    __syncthreads();
    for (int idx = tid; idx < NT; idx += 256) {
      int s = idx >> 4, i = idx & 15;
      xs[s*20 + i] = (xr[s*20 + i] - mu[s]) * rsd[s] * vg2[i] + vb2[i];
    }
    __syncthreads();
  }

  // ymap1 -> as_att [NB][84]
  for (int idx = tid; idx < 84; idx += 256) {
    int s = idx >> 2, j = idx & 3;
    float a = ymb[j];
    #pragma unroll
    for (int k = 0; k < 16; ++k) a += xs[s*20 + k] * ymw[j*16 + k];
    outp[(size_t)b*84 + idx] = a;
  }
}

// ---------------- Branch 2: mRNA, S=59, D=8, H=1 head, L=2 layers ----------------
__global__ __launch_bounds__(256) void b2_kernel(
    const float* __restrict__ inp,  // [NB][59][640]
    const float* __restrict__ xw,   // [8][640]
    const float* __restrict__ xb,   // [8]
    const float* __restrict__ qw,   // [2][24][8]
    const float* __restrict__ qb,   // [2][24]
    const float* __restrict__ ow,   // [2][8][8]
    const float* __restrict__ ob,   // [2][8]
    const float* __restrict__ f1w,  // [2][2048][8]
    const float* __restrict__ f1b,  // [2][2048]
    const float* __restrict__ f2w,  // [2][8][2048]
    const float* __restrict__ f2b,  // [2][8]
    const float* __restrict__ g1w,
    const float* __restrict__ b1w,
    const float* __restrict__ g2w,
    const float* __restrict__ b2w,
    const float* __restrict__ ymw,  // [1][8]
    const float* __restrict__ ymb,  // [1]
    float* __restrict__ outp)       // [NB][59]
{
  const int S = 59, D = 8, NT = S * D;   // 472
  __shared__ __align__(16) float xs[59*12];
  __shared__ __align__(16) float xr[59*12];
  __shared__ __align__(16) float qkv[59*28];
  __shared__ __align__(16) float sc[59*61];
  __shared__ __align__(16) float stageh[59*68];
  __shared__ __align__(16) float w2c[8*68];
  __shared__ __align__(16) float qkvw[24*12];
  __shared__ __align__(16) float owsb[8*12];
  __shared__ float vqb[24];
  __shared__ float vob[8], vg1[8], vb1[8], vg2[8], vb2[8], vf2b[8];
  __shared__ float mu[59], rsd[59];

  const int tid = threadIdx.x;
  const int b   = blockIdx.x;
  const float* A = inp + (size_t)b * 59 * 640;

  // ---------------- projection, 10 chunks of 64 cols ----------------
  float pacc0 = 0.f, pacc1 = 0.f;
  for (int c = 0; c < 10; ++c) {
    for (int idx = tid; idx < 59*16; idx += 256) {
      int s = idx >> 4, q4 = idx & 15;
      *(float4*)(stageh + s*68 + q4*4) = *(const float4*)(A + s*640 + c*64 + q4*4);
    }
    for (int idx = tid; idx < 8*16; idx += 256) {
      int i = idx >> 4, q4 = idx & 15;
      *(float4*)(w2c + i*68 + q4*4) = *(const float4*)(xw + i*640 + c*64 + q4*4);
    }
    __syncthreads();
    {
      int r = 0;
      for (int idx = tid; idx < NT; idx += 256, ++r) {
        int s = idx >> 3, i = idx & 7;
        float acc = 0.f;
        #pragma unroll
        for (int q = 0; q < 64; q += 4)
          acc += dot4f(*(const float4*)(stageh + s*68 + q), *(const float4*)(w2c + i*68 + q));
        if (r == 0) pacc0 += acc; else pacc1 += acc;
      }
    }
    __syncthreads();
  }
  {
    const float lf = -logf(10000.0f) / (float)D;
    int r = 0;
    for (int idx = tid; idx < NT; idx += 256, ++r) {
      int s = idx >> 3, i = idx & 7;
      float freq = expf((float)((i >> 1) * 2) * lf);
      float pe = (i & 1) ? cosf((float)s * freq) : sinf((float)s * freq);
      xs[s*12 + i] = ((r == 0) ? pacc0 : pacc1) + xb[i] + pe;
    }
  }
  __syncthreads();

  for (int L = 0; L < 2; ++L) {
    const float* qwL  = qw  + L*24*8;
    const float* f1wL = f1w + (size_t)L*2048*8;
    const float* f1bL = f1b + L*2048;
    const float* f2wL = f2w + (size_t)L*8*2048;

    for (int idx = tid; idx < 24*8; idx += 256) { int e = idx >> 3, k = idx & 7; qkvw[e*12+k] = qwL[idx]; }
    if (tid < 24) vqb[tid] = qb[L*24 + tid];
    if (tid < 64) { int i = tid >> 3, cc = tid & 7; owsb[i*12+cc] = ow[L*64 + tid]; }
    if (tid < 8) {
      vob[tid]  = ob[L*8+tid];  vg1[tid] = g1w[L*8+tid]; vb1[tid] = b1w[L*8+tid];
      vg2[tid]  = g2w[L*8+tid]; vb2[tid] = b2w[L*8+tid]; vf2b[tid] = f2b[L*8+tid];
    }
    __syncthreads();

    // qkv [59][24]
    for (int idx = tid; idx < 59*24; idx += 256) {
      int s = idx / 24, e = idx % 24;
      float a = vqb[e];
      #pragma unroll
      for (int k = 0; k < 8; ++k) a += xs[s*12+k] * qkvw[e*12+k];
      qkv[s*28 + e] = a;
    }
    __syncthreads();

    // scores [59][59], 1 head dh=8
    for (int idx = tid; idx < 59*59; idx += 256) {
      int i = idx / 59, j = idx % 59;
      float a = 0.f;
      #pragma unroll
      for (int c = 0; c < 8; ++c) a += qkv[i*28 + c] * qkv[j*28 + 8 + c];
      sc[i*61 + j] = a * 0.35355339059327373f;
    }
    __syncthreads();

    for (int r = tid; r < 59; r += 256) {
      float* row = sc + r*61;
      float m = row[0];
      for (int j = 1; j < 59; ++j) m = fmaxf(m, row[j]);
      float ssum = 0.f;
      for (int j = 0; j < 59; ++j) { float e = __expf(row[j] - m); row[j] = e; ssum += e; }
      float inv = 1.f / ssum;
      for (int j = 0; j < 59; ++j) row[j] *= inv;
    }
    __syncthreads();

    // attn out -> stageh [59][.] stride 68
    for (int idx = tid; idx < NT; idx += 256) {
      int s = idx >> 3, c = idx & 7;
      const float* row = sc + s*61;
      float a = 0.f;
      for (int j = 0; j < 59; ++j) a += row[j] * qkv[j*28 + 16 + c];
      stageh[s*68 + c] = a;
    }
    __syncthreads();

    for (int idx = tid; idx < NT; idx += 256) {
      int s = idx >> 3, i = idx & 7;
      float a = vob[i];
      #pragma unroll
      for (int c = 0; c < 8; ++c) a += stageh[s*68 + c] * owsb[i*12 + c];
      xr[s*12 + i] = xs[s*12 + i] + a;
    }
    __syncthreads();

    if (tid < 59) {
      float m = 0.f;
      #pragma unroll
      for (int k = 0; k < 8; ++k) m += xr[tid*12 + k];
      m *= 0.125f;
      float v = 0.f;
      #pragma unroll
      for (int k = 0; k < 8; ++k) { float d = xr[tid*12 + k] - m; v += d*d; }
      v *= 0.125f;
      mu[tid] = m; rsd[tid] = rsqrtf(v + 1e-5f);
    }
    __syncthreads();
    for (int idx = tid; idx < NT; idx += 256) {
      int s = idx >> 3, i = idx & 7;
      xs[s*12 + i] = (xr[s*12 + i] - mu[s]) * rsd[s] * vg1[i] + vb1[i];
    }
    __syncthreads();

    // FFN: 32 chunks of 64
    float facc0 = 0.f, facc1 = 0.f;
    for (int ch = 0; ch < 32; ++ch) {
      for (int idx = tid; idx < 8*16; idx += 256) {
        int i = idx >> 4, q4 = idx & 15;
        *(float4*)(w2c + i*68 + q4*4) = *(const float4*)(f2wL + i*2048 + ch*64 + q4*4);
      }
      __syncthreads();
      {
        int jj = tid & 63, tg = tid >> 6;   // 4 token groups
        int gj = ch*64 + jj;
        float4 w0 = *(const float4*)(f1wL + (size_t)gj*8 + 0);
        float4 w1 = *(const float4*)(f1wL + (size_t)gj*8 + 4);
        float bb = f1bL[gj];
        for (int t = tg; t < 59; t += 4) {
          float4 x0 = *(const float4*)(xs + t*12 + 0);
          float4 x1 = *(const float4*)(xs + t*12 + 4);
          float a = bb + dot4f(x0,w0) + dot4f(x1,w1);
          stageh[t*68 + jj] = fmaxf(a, 0.f);
        }
      }
      __syncthreads();
      {
        int r = 0;
        for (int idx = tid; idx < NT; idx += 256, ++r) {
          int t = idx >> 3, i = idx & 7;
          float a = 0.f;
          #pragma unroll
          for (int q = 0; q < 64; q += 4)
            a += dot4f(*(const float4*)(stageh + t*68 + q), *(const float4*)(w2c + i*68 + q));
          if (r == 0) facc0 += a; else facc1 += a;
        }
      }
      __syncthreads();
    }
    {
      int r = 0;
      for (int idx = tid; idx < NT; idx += 256, ++r) {
        int t = idx >> 3, i = idx & 7;
        xr[t*12 + i] = xs[t*12 + i] + ((r == 0) ? facc0 : facc1) + vf2b[i];
      }
    }
    __syncthreads();
    if (tid < 59) {
      float m = 0.f;
      #pragma unroll
      for (int k = 0; k < 8; ++k) m += xr[tid*12 + k];
      m *= 0.125f;
      float v = 0.f;
      #pragma unroll
      for (int k = 0; k < 8; ++k) { float d = xr[tid*12 + k] - m; v += d*d; }
      v *= 0.125f;
      mu[tid] = m; rsd[tid] = rsqrtf(v + 1e-5f);
    }
    __syncthreads();
    for (int idx = tid; idx < NT; idx += 256) {
      int s = idx >> 3, i = idx & 7;
      xs[s*12 + i] = (xr[s*12 + i] - mu[s]) * rsd[s] * vg2[i] + vb2[i];
    }
    __syncthreads();
  }

  // ymap2 -> mrna_att [NB][59]
  for (int s = tid; s < 59; s += 256) {
    float a = ymb[0];
    #pragma unroll
    for (int k = 0; k < 8; ++k) a += xs[s*12 + k] * ymw[k];
    outp[(size_t)b*59 + s] = a;
  }
}

// ---------------- Final MLP head ----------------
__global__ __launch_bounds__(256) void mlp_kernel(
    const float* __restrict__ as_att,   // [NB][84]
    const float* __restrict__ mrna,     // [NB][59]
    const float* __restrict__ f_gibbs,  // [NB][19]
    const float* __restrict__ f_pssm,   // [NB][1]
    const float* __restrict__ f_gcs,    // [NB][1]
    const float* __restrict__ f_ssp,    // [NB][2]
    const float* __restrict__ f_sse,    // [NB][2]
    const float* __restrict__ f_tri,    // [NB][64]
    const float* __restrict__ f_di,     // [NB][16]
    const float* __restrict__ f_sgl,    // [NB][4]
    const float* __restrict__ f_gc,     // [NB][1]
    const float* __restrict__ bn_g, const float* __restrict__ bn_b,
    const float* __restrict__ d1w, const float* __restrict__ d1b,
    const float* __restrict__ d2w, const float* __restrict__ d2b,
    const float* __restrict__ d3w, const float* __restrict__ d3b,
    const float* __restrict__ d4w, const float* __restrict__ d4b,
    float* __restrict__ outp)           // [NB]
{
  __shared__ float cat[256];
  __shared__ float l1[256];
  __shared__ float l2[64];
  __shared__ float l3[16];
  const int tid = threadIdx.x;
  const int b   = blockIdx.x;
  const float bnscale = rsqrtf(1.0f + 1e-5f);

  if (tid < 253) {
    float v;
    if (tid < 84)       v = as_att[(size_t)b*84 + tid];
    else if (tid < 143) v = mrna[(size_t)b*59 + (tid - 84)];
    else {
      int j = tid - 143;
      if (j < 19)       v = f_gibbs[b*19 + j];
      else if (j < 20)  v = f_pssm[b];
      else if (j < 21)  v = f_gcs[b];
      else if (j < 23)  v = f_ssp[b*2 + (j-21)];
      else if (j < 25)  v = f_sse[b*2 + (j-23)];
      else if (j < 89)  v = f_tri[b*64 + (j-25)];
      else if (j < 105) v = f_di[b*16 + (j-89)];
      else if (j < 109) v = f_sgl[b*4 + (j-105)];
      else              v = f_gc[b];
    }
    cat[tid] = v * bnscale * bn_g[tid] + bn_b[tid];
  }
  __syncthreads();

  { // d1: 253 -> 256, leaky relu
    float a = d1b[tid];
    const float* w = d1w + (size_t)tid * 253;
    for (int j = 0; j < 253; ++j) a += cat[j] * w[j];
    l1[tid] = (a > 0.f) ? a : 0.01f * a;
  }
  __syncthreads();
  if (tid < 64) { // d2: 256 -> 64
    float a = d2b[tid];
    const float* w = d2w + (size_t)tid * 256;
    for (int j = 0; j < 256; ++j) a += l1[j] * w[j];
    l2[tid] = (a > 0.f) ? a : 0.01f * a;
  }
  __syncthreads();
  if (tid < 16) { // d3: 64 -> 16
    float a = d3b[tid];
    const float* w = d3w + tid * 64;
    for (int j = 0; j < 64; ++j) a += l2[j] * w[j];
    l3[tid] = (a > 0.f) ? a : 0.01f * a;
  }
  __syncthreads();
  if (tid == 0) { // d4: 16 -> 1, sigmoid
    float a = d4b[0];
    #pragma unroll
    for (int j = 0; j < 16; ++j) a += l3[j] * d4w[j];
    outp[b] = 1.f / (1.f + __expf(-a));
  }
}

extern "C" void kernel_launch(void* const* d_in, const int* in_sizes, int n_in,
                              void* d_out, int out_size, void* d_ws, size_t ws_size,
                              hipStream_t stream) {
  const float* rnafm   = (const float*)d_in[0];
  const float* rnafm_m = (const float*)d_in[1];
  const float* f_gibbs = (const float*)d_in[2];
  const float* f_pssm  = (const float*)d_in[3];
  const float* f_gcs   = (const float*)d_in[4];
  const float* f_ssp   = (const float*)d_in[5];
  const float* f_sse   = (const float*)d_in[6];
  const float* f_tri   = (const float*)d_in[7];
  const float* f_di    = (const float*)d_in[8];
  const float* f_sgl   = (const float*)d_in[9];
  const float* f_gc    = (const float*)d_in[10];
  const float* xmap1_w = (const float*)d_in[11];
  const float* xmap1_b = (const float*)d_in[12];
  const float* e1_qw   = (const float*)d_in[13];
  const float* e1_qb   = (const float*)d_in[14];
  const float* e1_ow   = (const float*)d_in[15];
  const float* e1_ob   = (const float*)d_in[16];
  const float* e1_f1w  = (const float*)d_in[17];
  const float* e1_f1b  = (const float*)d_in[18];
  const float* e1_f2w  = (const float*)d_in[19];
  const float* e1_f2b  = (const float*)d_in[20];
  const float* e1_g1   = (const float*)d_in[21];
  const float* e1_b1   = (const float*)d_in[22];
  const float* e1_g2   = (const float*)d_in[23];
  const float* e1_b2   = (const float*)d_in[24];
  const float* ymap1_w = (const float*)d_in[25];
  const float* ymap1_b = (const float*)d_in[26];
  const float* xmap2_w = (const float*)d_in[27];
  const float* xmap2_b = (const float*)d_in[28];
  const float* e2_qw   = (const float*)d_in[29];
  const float* e2_qb   = (const float*)d_in[30];
  const float* e2_ow   = (const float*)d_in[31];
  const float* e2_ob   = (const float*)d_in[32];
  const float* e2_f1w  = (const float*)d_in[33];
  const float* e2_f1b  = (const float*)d_in[34];
  const float* e2_f2w  = (const float*)d_in[35];
  const float* e2_f2b  = (const float*)d_in[36];
  const float* e2_g1   = (const float*)d_in[37];
  const float* e2_b1   = (const float*)d_in[38];
  const float* e2_g2   = (const float*)d_in[39];
  const float* e2_b2   = (const float*)d_in[40];
  const float* ymap2_w = (const float*)d_in[41];
  const float* ymap2_b = (const float*)d_in[42];
  const float* bn_g    = (const float*)d_in[43];
  const float* bn_b    = (const float*)d_in[44];
  const float* d1w     = (const float*)d_in[45];
  const float* d1b     = (const float*)d_in[46];
  const float* d2w     = (const float*)d_in[47];
  const float* d2b     = (const float*)d_in[48];
  const float* d3w     = (const float*)d_in[49];
  const float* d3b     = (const float*)d_in[50];
  const float* d4w     = (const float*)d_in[51];
  const float* d4b     = (const float*)d_in[52];

  float* ws      = (float*)d_ws;
  float* as_att  = ws;                 // NB*84 floats
  float* mrna    = ws + (size_t)NB*84; // NB*59 floats
  float* outp    = (float*)d_out;

  b1_kernel<<<NB, 256, 0, stream>>>(rnafm, xmap1_w, xmap1_b,
      e1_qw, e1_qb, e1_ow, e1_ob, e1_f1w, e1_f1b, e1_f2w, e1_f2b,
      e1_g1, e1_b1, e1_g2, e1_b2, ymap1_w, ymap1_b, as_att);

  b2_kernel<<<NB, 256, 0, stream>>>(rnafm_m, xmap2_w, xmap2_b,
      e2_qw, e2_qb, e2_ow, e2_ob, e2_f1w, e2_f1b, e2_f2w, e2_f2b,
      e2_g1, e2_b1, e2_g2, e2_b2, ymap2_w, ymap2_b, mrna);

  mlp_kernel<<<NB, 256, 0, stream>>>(as_att, mrna,
      f_gibbs, f_pssm, f_gcs, f_ssp, f_sse, f_tri, f_di, f_sgl, f_gc,
      bn_g, bn_b, d1w, d1b, d2w, d2b, d3w, d3b, d4w, d4b, outp);
}

// Round 2
// 573.874 us; speedup vs baseline: 2.7598x; 2.7598x over previous
//
#include <hip/hip_runtime.h>
#include <math.h>

#define NB 1024

typedef __bf16 mbf8 __attribute__((ext_vector_type(8)));
typedef float  mf4  __attribute__((ext_vector_type(4)));

union Pk { __bf16 h[4]; uint2 u2; };

__device__ __forceinline__ mf4 mfma16(mbf8 a, mbf8 b, mf4 c) {
  return __builtin_amdgcn_mfma_f32_16x16x32_bf16(a, b, c, 0, 0, 0);
}

__device__ __forceinline__ float dot4f(float4 a, float4 b){
  return a.x*b.x + a.y*b.y + a.z*b.z + a.w*b.w;
}

// ---------------- prep: fp32 weights -> bf16 MFMA fragments in ws ----------------
// layout of each fragment tile: [64 lanes][8 j] ; A/B frag element = [m|n = lane&15][k = (lane>>4)*8 + j]
// segments (element offsets into out):
//  0      : xw1B  [20 ks][64][8]           (B-frag, n=out<16, k=ks*32+khi<640)
//  10240  : w1B1  [4L][128 nt][64][8]      (A-frag, m=unit, k=khi real<16)
//  272384 : w2B1  [4L][64 ks][64][8]       (B-frag, n=out<16, k=ks*32+khi<2048)
//  403456 : xw2B  [20 ks][64][8]           (B-frag, n=out real<8)
//  413696 : w1B2  [2L][128 nt][64][8]      (A-frag, k real<8)
//  544768 : w2B2  [2L][64 ks][64][8]       (B-frag, n real<8)
__global__ __launch_bounds__(256) void prep_kernel(
    const float* __restrict__ xw1, const float* __restrict__ f1w1, const float* __restrict__ f2w1,
    const float* __restrict__ xw2, const float* __restrict__ f1w2, const float* __restrict__ f2w2,
    __bf16* __restrict__ out)
{
  int idx = blockIdx.x * 256 + threadIdx.x;
  if (idx >= 610304) return;
  int which, local;
  if (idx < 10240)       { which = 0; local = idx; }
  else if (idx < 272384) { which = 1; local = idx - 10240; }
  else if (idx < 403456) { which = 2; local = idx - 272384; }
  else if (idx < 413696) { which = 3; local = idx - 403456; }
  else if (idx < 544768) { which = 4; local = idx - 413696; }
  else                   { which = 5; local = idx - 544768; }
  int tile = local >> 9, r = local & 511, lane = r >> 3, j = r & 7;
  int quad = lane >> 4, lm = lane & 15, khi = quad * 8 + j;
  float val = 0.f;
  switch (which) {
    case 0: { int k = tile*32 + khi; val = xw1[lm*640 + k]; } break;
    case 1: { int L = tile >> 7, nt = tile & 127, n = nt*16 + lm;
              val = (khi < 16) ? f1w1[(L*2048 + n)*16 + khi] : 0.f; } break;
    case 2: { int L = tile >> 6, ks = tile & 63, k = ks*32 + khi;
              val = f2w1[(L*16 + lm)*2048 + k]; } break;
    case 3: { int k = tile*32 + khi; val = (lm < 8) ? xw2[lm*640 + k] : 0.f; } break;
    case 4: { int L = tile >> 7, nt = tile & 127, n = nt*16 + lm;
              val = (khi < 8) ? f1w2[(L*2048 + n)*8 + khi] : 0.f; } break;
    default:{ int L = tile >> 6, ks = tile & 63, k = ks*32 + khi;
              val = (lm < 8) ? f2w2[(L*8 + lm)*2048 + k] : 0.f; } break;
  }
  out[idx] = (__bf16)val;
}

// ---------------- Branch 1: siRNA, S=21, D=16, H=2, L=4 ----------------
__global__ __launch_bounds__(256) void b1_kernel(
    const float* __restrict__ inp,
    const float* __restrict__ xb,
    const float* __restrict__ qw, const float* __restrict__ qb,
    const float* __restrict__ ow, const float* __restrict__ ob,
    const float* __restrict__ f1b, const float* __restrict__ f2b,
    const float* __restrict__ g1w, const float* __restrict__ b1w,
    const float* __restrict__ g2w, const float* __restrict__ b2w,
    const float* __restrict__ ymw, const float* __restrict__ ymb,
    const __bf16* __restrict__ xwB, const __bf16* __restrict__ w1B,
    const __bf16* __restrict__ w2B,
    float* __restrict__ outp)
{
  __shared__ __align__(16) float xs[21*20];
  __shared__ __align__(16) float xr[21*20];
  __shared__ __align__(16) float ao[21*20];
  __shared__ __align__(16) float pool[2176];   // qkv(21*52)+sc(2*21*23) | red(4*2*16*17)
  __shared__ __align__(16) __bf16 hbuf[32*264];
  __shared__ float mu[21], rsd[21];

  const int tid = threadIdx.x;
  const int b = blockIdx.x;
  const int w = tid >> 6, lane = tid & 63, quad = lane >> 4, lm = lane & 15;
  float* qkv = pool;           // [21][52]
  float* sc  = pool + 1092;    // [42][23]
  float* red = pool;           // [4][2][16][17]
  const float* Ain = inp + (size_t)b * 21 * 640;

  // ---- input projection via MFMA: x[21,640] @ xw^T[640,16], K split over waves ----
  mf4 pc0 = {0.f,0.f,0.f,0.f}, pc1 = {0.f,0.f,0.f,0.f};
  for (int i = 0; i < 5; ++i) {
    int ks = w*5 + i;
    mbf8 bv = *(const mbf8*)(xwB + (ks*64 + lane)*8);
    #pragma unroll
    for (int mt = 0; mt < 2; ++mt) {
      int row = mt*16 + lm; row = row > 20 ? 20 : row;
      const float* src = Ain + row*640 + ks*32 + quad*8;
      float4 u0 = *(const float4*)src;
      float4 u1 = *(const float4*)(src + 4);
      mbf8 av;
      av[0]=(__bf16)u0.x; av[1]=(__bf16)u0.y; av[2]=(__bf16)u0.z; av[3]=(__bf16)u0.w;
      av[4]=(__bf16)u1.x; av[5]=(__bf16)u1.y; av[6]=(__bf16)u1.z; av[7]=(__bf16)u1.w;
      if (mt == 0) pc0 = mfma16(av, bv, pc0); else pc1 = mfma16(av, bv, pc1);
    }
  }
  #pragma unroll
  for (int r = 0; r < 4; ++r) {
    red[((w*2+0)*16 + quad*4 + r)*17 + lm] = pc0[r];
    red[((w*2+1)*16 + quad*4 + r)*17 + lm] = pc1[r];
  }
  __syncthreads();
  {
    const float lf = -logf(10000.0f) / 16.0f;
    for (int idx = tid; idx < 336; idx += 256) {
      int t = idx >> 4, i = idx & 15, mt = t >> 4, tl = t & 15;
      float s = red[((0+mt)*16+tl)*17+i] + red[((2+mt)*16+tl)*17+i]
              + red[((4+mt)*16+tl)*17+i] + red[((6+mt)*16+tl)*17+i];
      float freq = expf((float)((i>>1)*2) * lf);
      float pe = (i & 1) ? cosf((float)t * freq) : sinf((float)t * freq);
      xs[t*20 + i] = s + xb[i] + pe;
    }
  }
  __syncthreads();

  for (int L = 0; L < 4; ++L) {
    // qkv = x @ qkv_w^T + b -> [21][48]
    for (int idx = tid; idx < 1008; idx += 256) {
      int s = idx / 48, e = idx % 48;
      const float* wr = qw + (L*48 + e)*16;
      float a = qb[L*48 + e];
      #pragma unroll
      for (int k = 0; k < 16; ++k) a += xs[s*20+k] * wr[k];
      qkv[s*52 + e] = a;
    }
    __syncthreads();

    // scores, 2 heads dh=8
    for (int idx = tid; idx < 882; idx += 256) {
      int h = idx / 441, r2 = idx % 441, i = r2 / 21, j = r2 % 21;
      float4 q0 = *(const float4*)(qkv + i*52 + h*8);
      float4 q1 = *(const float4*)(qkv + i*52 + h*8 + 4);
      float4 k0 = *(const float4*)(qkv + j*52 + 16 + h*8);
      float4 k1 = *(const float4*)(qkv + j*52 + 16 + h*8 + 4);
      sc[(h*21 + i)*23 + j] = (dot4f(q0,k0) + dot4f(q1,k1)) * 0.35355339059327373f;
    }
    __syncthreads();

    for (int r = tid; r < 42; r += 256) {
      float* row = sc + r*23;
      float m = row[0];
      for (int j = 1; j < 21; ++j) m = fmaxf(m, row[j]);
      float ssum = 0.f;
      for (int j = 0; j < 21; ++j) { float e = __expf(row[j] - m); row[j] = e; ssum += e; }
      float inv = 1.f / ssum;
      for (int j = 0; j < 21; ++j) row[j] *= inv;
    }
    __syncthreads();

    for (int idx = tid; idx < 336; idx += 256) {
      int s = idx >> 4, cc = idx & 15, h = cc >> 3, c = cc & 7;
      const float* row = sc + (h*21 + s)*23;
      float a = 0.f;
      for (int j = 0; j < 21; ++j) a += row[j] * qkv[j*52 + 32 + h*8 + c];
      ao[s*20 + cc] = a;
    }
    __syncthreads();

    for (int idx = tid; idx < 336; idx += 256) {
      int s = idx >> 4, i = idx & 15;
      const float* wr = ow + (L*16 + i)*16;
      float a = ob[L*16 + i];
      #pragma unroll
      for (int c = 0; c < 16; ++c) a += ao[s*20 + c] * wr[c];
      xr[s*20 + i] = xs[s*20 + i] + a;
    }
    __syncthreads();

    if (tid < 21) {
      float m = 0.f;
      #pragma unroll
      for (int k = 0; k < 16; ++k) m += xr[tid*20 + k];
      m *= (1.f/16.f);
      float v = 0.f;
      #pragma unroll
      for (int k = 0; k < 16; ++k) { float d = xr[tid*20 + k] - m; v += d*d; }
      v *= (1.f/16.f);
      mu[tid] = m; rsd[tid] = rsqrtf(v + 1e-5f);
    }
    __syncthreads();
    for (int idx = tid; idx < 336; idx += 256) {
      int s = idx >> 4, i = idx & 15;
      xs[s*20 + i] = (xr[s*20 + i] - mu[s]) * rsd[s] * g1w[L*16+i] + b1w[L*16+i];
    }
    __syncthreads();

    // ---- FFN via MFMA (barrier-free inner loop; wave-aligned K split) ----
    mbf8 xf0, xf1;
    {
      #pragma unroll
      for (int q = 0; q < 8; ++q) { xf0[q] = (__bf16)0.f; xf1[q] = (__bf16)0.f; }
      if (quad < 2) {
        int t0 = lm;               // tokens 0..15
        int t1 = 16 + lm; if (t1 > 20) t1 = 20;
        const float* s0 = xs + t0*20 + quad*8;
        const float* s1 = xs + t1*20 + quad*8;
        float4 a0 = *(const float4*)s0, a1 = *(const float4*)(s0+4);
        float4 b0 = *(const float4*)s1, b1_ = *(const float4*)(s1+4);
        xf0[0]=(__bf16)a0.x; xf0[1]=(__bf16)a0.y; xf0[2]=(__bf16)a0.z; xf0[3]=(__bf16)a0.w;
        xf0[4]=(__bf16)a1.x; xf0[5]=(__bf16)a1.y; xf0[6]=(__bf16)a1.z; xf0[7]=(__bf16)a1.w;
        xf1[0]=(__bf16)b0.x; xf1[1]=(__bf16)b0.y; xf1[2]=(__bf16)b0.z; xf1[3]=(__bf16)b0.w;
        xf1[4]=(__bf16)b1_.x; xf1[5]=(__bf16)b1_.y; xf1[6]=(__bf16)b1_.z; xf1[7]=(__bf16)b1_.w;
      }
    }
    mf4 of0 = {0.f,0.f,0.f,0.f}, of1 = {0.f,0.f,0.f,0.f};
    const __bf16* w1L = w1B + (size_t)L*128*512;
    const __bf16* w2L = w2B + (size_t)L*64*512;
    const float* f1bL = f1b + L*2048;
    for (int ci = 0; ci < 8; ++ci) {
      // phase A: h^T tiles for units [ci*256 + w*64, +64)
      #pragma unroll
      for (int u = 0; u < 4; ++u) {
        int ut = ci*16 + w*4 + u;
        mbf8 wa = *(const mbf8*)(w1L + (ut*64 + lane)*8);
        float4 bia = *(const float4*)(f1bL + ut*16 + quad*4);
        mf4 z = {0.f,0.f,0.f,0.f};
        mf4 c0 = mfma16(wa, xf0, z);
        mf4 c1 = mfma16(wa, xf1, z);
        Pk p0, p1;
        p0.h[0]=(__bf16)fmaxf(c0[0]+bia.x,0.f); p0.h[1]=(__bf16)fmaxf(c0[1]+bia.y,0.f);
        p0.h[2]=(__bf16)fmaxf(c0[2]+bia.z,0.f); p0.h[3]=(__bf16)fmaxf(c0[3]+bia.w,0.f);
        p1.h[0]=(__bf16)fmaxf(c1[0]+bia.x,0.f); p1.h[1]=(__bf16)fmaxf(c1[1]+bia.y,0.f);
        p1.h[2]=(__bf16)fmaxf(c1[2]+bia.z,0.f); p1.h[3]=(__bf16)fmaxf(c1[3]+bia.w,0.f);
        int colb = (ut & 15)*16 + quad*4;
        *(uint2*)(hbuf + lm*264 + colb)        = p0.u2;
        *(uint2*)(hbuf + (16 + lm)*264 + colb) = p1.u2;
      }
      // phase B: this wave consumes exactly the columns it wrote (k in [w*64, w*64+64))
      #pragma unroll
      for (int kk = 0; kk < 2; ++kk) {
        int ksl = w*2 + kk;
        mbf8 wb = *(const mbf8*)(w2L + ((ci*8 + ksl)*64 + lane)*8);
        mbf8 a0 = *(const mbf8*)(hbuf + lm*264 + ksl*32 + quad*8);
        mbf8 a1 = *(const mbf8*)(hbuf + (16 + lm)*264 + ksl*32 + quad*8);
        of0 = mfma16(a0, wb, of0);
        of1 = mfma16(a1, wb, of1);
      }
    }
    __syncthreads();   // pool (sc/qkv) dead; red reuse
    #pragma unroll
    for (int r = 0; r < 4; ++r) {
      red[((w*2+0)*16 + quad*4 + r)*17 + lm] = of0[r];
      red[((w*2+1)*16 + quad*4 + r)*17 + lm] = of1[r];
    }
    __syncthreads();
    for (int idx = tid; idx < 336; idx += 256) {
      int t = idx >> 4, i = idx & 15, mt = t >> 4, tl = t & 15;
      float s = red[((0+mt)*16+tl)*17+i] + red[((2+mt)*16+tl)*17+i]
              + red[((4+mt)*16+tl)*17+i] + red[((6+mt)*16+tl)*17+i];
      xr[t*20 + i] = xs[t*20 + i] + s + f2b[L*16 + i];
    }
    __syncthreads();
    if (tid < 21) {
      float m = 0.f;
      #pragma unroll
      for (int k = 0; k < 16; ++k) m += xr[tid*20 + k];
      m *= (1.f/16.f);
      float v = 0.f;
      #pragma unroll
      for (int k = 0; k < 16; ++k) { float d = xr[tid*20 + k] - m; v += d*d; }
      v *= (1.f/16.f);
      mu[tid] = m; rsd[tid] = rsqrtf(v + 1e-5f);
    }
    __syncthreads();
    for (int idx = tid; idx < 336; idx += 256) {
      int s = idx >> 4, i = idx & 15;
      xs[s*20 + i] = (xr[s*20 + i] - mu[s]) * rsd[s] * g2w[L*16+i] + b2w[L*16+i];
    }
    __syncthreads();
  }

  for (int idx = tid; idx < 84; idx += 256) {
    int s = idx >> 2, j = idx & 3;
    float a = ymb[j];
    #pragma unroll
    for (int k = 0; k < 16; ++k) a += xs[s*20 + k] * ymw[j*16 + k];
    outp[(size_t)b*84 + idx] = a;
  }
}

// ---------------- Branch 2: mRNA, S=59, D=8, H=1, L=2 ----------------
__global__ __launch_bounds__(256) void b2_kernel(
    const float* __restrict__ inp,
    const float* __restrict__ xb,
    const float* __restrict__ qw, const float* __restrict__ qb,
    const float* __restrict__ ow, const float* __restrict__ ob,
    const float* __restrict__ f1b, const float* __restrict__ f2b,
    const float* __restrict__ g1w, const float* __restrict__ b1w,
    const float* __restrict__ g2w, const float* __restrict__ b2w,
    const float* __restrict__ ymw, const float* __restrict__ ymb,
    const __bf16* __restrict__ xwB, const __bf16* __restrict__ w1B,
    const __bf16* __restrict__ w2B,
    float* __restrict__ outp)
{
  __shared__ __align__(16) float xs[59*12];
  __shared__ __align__(16) float xr[59*12];
  __shared__ __align__(16) float ao[59*12];
  __shared__ __align__(16) float pool[5251];   // qkv(59*28)+sc(59*61) | red(4*4*16*17=4352)
  __shared__ __align__(16) __bf16 hbuf[64*136];
  __shared__ float mu[59], rsd[59];

  const int tid = threadIdx.x;
  const int b = blockIdx.x;
  const int w = tid >> 6, lane = tid & 63, quad = lane >> 4, lm = lane & 15;
  float* qkv = pool;          // [59][28]
  float* sc  = pool + 1652;   // [59][61]
  float* red = pool;          // [4][4][16][17]
  const float* Ain = inp + (size_t)b * 59 * 640;

  // ---- projection: x[59,640] @ xw^T[640,8] ----
  mf4 pc[4];
  #pragma unroll
  for (int mt = 0; mt < 4; ++mt) { mf4 z = {0.f,0.f,0.f,0.f}; pc[mt] = z; }
  for (int i = 0; i < 5; ++i) {
    int ks = w*5 + i;
    mbf8 bv = *(const mbf8*)(xwB + (ks*64 + lane)*8);
    #pragma unroll
    for (int mt = 0; mt < 4; ++mt) {
      int row = mt*16 + lm; row = row > 58 ? 58 : row;
      const float* src = Ain + row*640 + ks*32 + quad*8;
      float4 u0 = *(const float4*)src;
      float4 u1 = *(const float4*)(src + 4);
      mbf8 av;
      av[0]=(__bf16)u0.x; av[1]=(__bf16)u0.y; av[2]=(__bf16)u0.z; av[3]=(__bf16)u0.w;
      av[4]=(__bf16)u1.x; av[5]=(__bf16)u1.y; av[6]=(__bf16)u1.z; av[7]=(__bf16)u1.w;
      pc[mt] = mfma16(av, bv, pc[mt]);
    }
  }
  #pragma unroll
  for (int mt = 0; mt < 4; ++mt)
    #pragma unroll
    for (int r = 0; r < 4; ++r)
      red[((w*4+mt)*16 + quad*4 + r)*17 + lm] = pc[mt][r];
  __syncthreads();
  {
    const float lf = -logf(10000.0f) / 8.0f;
    for (int idx = tid; idx < 472; idx += 256) {
      int t = idx >> 3, i = idx & 7, mt = t >> 4, tl = t & 15;
      float s = red[((0*4+mt)*16+tl)*17+i] + red[((1*4+mt)*16+tl)*17+i]
              + red[((2*4+mt)*16+tl)*17+i] + red[((3*4+mt)*16+tl)*17+i];
      float freq = expf((float)((i>>1)*2) * lf);
      float pe = (i & 1) ? cosf((float)t * freq) : sinf((float)t * freq);
      xs[t*12 + i] = s + xb[i] + pe;
    }
  }
  __syncthreads();

  for (int L = 0; L < 2; ++L) {
    for (int idx = tid; idx < 1416; idx += 256) {
      int s = idx / 24, e = idx % 24;
      const float* wr = qw + (L*24 + e)*8;
      float a = qb[L*24 + e];
      #pragma unroll
      for (int k = 0; k < 8; ++k) a += xs[s*12+k] * wr[k];
      qkv[s*28 + e] = a;
    }
    __syncthreads();

    for (int idx = tid; idx < 3481; idx += 256) {
      int i = idx / 59, j = idx % 59;
      float4 q0 = *(const float4*)(qkv + i*28);
      float4 q1 = *(const float4*)(qkv + i*28 + 4);
      float4 k0 = *(const float4*)(qkv + j*28 + 8);
      float4 k1 = *(const float4*)(qkv + j*28 + 12);
      sc[i*61 + j] = (dot4f(q0,k0) + dot4f(q1,k1)) * 0.35355339059327373f;
    }
    __syncthreads();

    for (int r = tid; r < 59; r += 256) {
      float* row = sc + r*61;
      float m = row[0];
      for (int j = 1; j < 59; ++j) m = fmaxf(m, row[j]);
      float ssum = 0.f;
      for (int j = 0; j < 59; ++j) { float e = __expf(row[j] - m); row[j] = e; ssum += e; }
      float inv = 1.f / ssum;
      for (int j = 0; j < 59; ++j) row[j] *= inv;
    }
    __syncthreads();

    for (int idx = tid; idx < 472; idx += 256) {
      int s = idx >> 3, c = idx & 7;
      const float* row = sc + s*61;
      float a = 0.f;
      for (int j = 0; j < 59; ++j) a += row[j] * qkv[j*28 + 16 + c];
      ao[s*12 + c] = a;
    }
    __syncthreads();

    for (int idx = tid; idx < 472; idx += 256) {
      int s = idx >> 3, i = idx & 7;
      const float* wr = ow + (L*8 + i)*8;
      float a = ob[L*8 + i];
      #pragma unroll
      for (int c = 0; c < 8; ++c) a += ao[s*12 + c] * wr[c];
      xr[s*12 + i] = xs[s*12 + i] + a;
    }
    __syncthreads();

    if (tid < 59) {
      float m = 0.f;
      #pragma unroll
      for (int k = 0; k < 8; ++k) m += xr[tid*12 + k];
      m *= 0.125f;
      float v = 0.f;
      #pragma unroll
      for (int k = 0; k < 8; ++k) { float d = xr[tid*12 + k] - m; v += d*d; }
      v *= 0.125f;
      mu[tid] = m; rsd[tid] = rsqrtf(v + 1e-5f);
    }
    __syncthreads();
    for (int idx = tid; idx < 472; idx += 256) {
      int s = idx >> 3, i = idx & 7;
      xs[s*12 + i] = (xr[s*12 + i] - mu[s]) * rsd[s] * g1w[L*8+i] + b1w[L*8+i];
    }
    __syncthreads();

    // ---- FFN via MFMA ----
    mbf8 xf[4];
    #pragma unroll
    for (int tt = 0; tt < 4; ++tt) {
      #pragma unroll
      for (int q = 0; q < 8; ++q) xf[tt][q] = (__bf16)0.f;
      if (quad == 0) {
        int tok = tt*16 + lm; if (tok > 58) tok = 58;
        const float* src = xs + tok*12;
        float4 u0 = *(const float4*)src, u1 = *(const float4*)(src + 4);
        xf[tt][0]=(__bf16)u0.x; xf[tt][1]=(__bf16)u0.y; xf[tt][2]=(__bf16)u0.z; xf[tt][3]=(__bf16)u0.w;
        xf[tt][4]=(__bf16)u1.x; xf[tt][5]=(__bf16)u1.y; xf[tt][6]=(__bf16)u1.z; xf[tt][7]=(__bf16)u1.w;
      }
    }
    mf4 of[4];
    #pragma unroll
    for (int mt = 0; mt < 4; ++mt) { mf4 z = {0.f,0.f,0.f,0.f}; of[mt] = z; }
    const __bf16* w1L = w1B + (size_t)L*128*512;
    const __bf16* w2L = w2B + (size_t)L*64*512;
    const float* f1bL = f1b + L*2048;
    for (int ci = 0; ci < 16; ++ci) {
      #pragma unroll
      for (int u = 0; u < 2; ++u) {
        int ut = ci*8 + w*2 + u;
        mbf8 wa = *(const mbf8*)(w1L + (ut*64 + lane)*8);
        float4 bia = *(const float4*)(f1bL + ut*16 + quad*4);
        int colb = (ut & 7)*16 + quad*4;
        #pragma unroll
        for (int tt = 0; tt < 4; ++tt) {
          mf4 z = {0.f,0.f,0.f,0.f};
          mf4 c = mfma16(wa, xf[tt], z);
          Pk p;
          p.h[0]=(__bf16)fmaxf(c[0]+bia.x,0.f); p.h[1]=(__bf16)fmaxf(c[1]+bia.y,0.f);
          p.h[2]=(__bf16)fmaxf(c[2]+bia.z,0.f); p.h[3]=(__bf16)fmaxf(c[3]+bia.w,0.f);
          *(uint2*)(hbuf + (tt*16 + lm)*136 + colb) = p.u2;
        }
      }
      // phase B: wave w consumes k columns [w*32, w*32+32) of this chunk (own writes)
      {
        mbf8 wb = *(const mbf8*)(w2L + ((ci*4 + w)*64 + lane)*8);
        #pragma unroll
        for (int mt = 0; mt < 4; ++mt) {
          mbf8 ah = *(const mbf8*)(hbuf + (mt*16 + lm)*136 + w*32 + quad*8);
          of[mt] = mfma16(ah, wb, of[mt]);
        }
      }
    }
    __syncthreads();
    #pragma unroll
    for (int mt = 0; mt < 4; ++mt)
      #pragma unroll
      for (int r = 0; r < 4; ++r)
        red[((w*4+mt)*16 + quad*4 + r)*17 + lm] = of[mt][r];
    __syncthreads();
    for (int idx = tid; idx < 472; idx += 256) {
      int t = idx >> 3, i = idx & 7, mt = t >> 4, tl = t & 15;
      float s = red[((0*4+mt)*16+tl)*17+i] + red[((1*4+mt)*16+tl)*17+i]
              + red[((2*4+mt)*16+tl)*17+i] + red[((3*4+mt)*16+tl)*17+i];
      xr[t*12 + i] = xs[t*12 + i] + s + f2b[L*8 + i];
    }
    __syncthreads();
    if (tid < 59) {
      float m = 0.f;
      #pragma unroll
      for (int k = 0; k < 8; ++k) m += xr[tid*12 + k];
      m *= 0.125f;
      float v = 0.f;
      #pragma unroll
      for (int k = 0; k < 8; ++k) { float d = xr[tid*12 + k] - m; v += d*d; }
      v *= 0.125f;
      mu[tid] = m; rsd[tid] = rsqrtf(v + 1e-5f);
    }
    __syncthreads();
    for (int idx = tid; idx < 472; idx += 256) {
      int s = idx >> 3, i = idx & 7;
      xs[s*12 + i] = (xr[s*12 + i] - mu[s]) * rsd[s] * g2w[L*8+i] + b2w[L*8+i];
    }
    __syncthreads();
  }

  for (int s = tid; s < 59; s += 256) {
    float a = ymb[0];
    #pragma unroll
    for (int k = 0; k < 8; ++k) a += xs[s*12 + k] * ymw[k];
    outp[(size_t)b*59 + s] = a;
  }
}

// ---------------- Final MLP head ----------------
__global__ __launch_bounds__(256) void mlp_kernel(
    const float* __restrict__ as_att, const float* __restrict__ mrna,
    const float* __restrict__ f_gibbs, const float* __restrict__ f_pssm,
    const float* __restrict__ f_gcs, const float* __restrict__ f_ssp,
    const float* __restrict__ f_sse, const float* __restrict__ f_tri,
    const float* __restrict__ f_di, const float* __restrict__ f_sgl,
    const float* __restrict__ f_gc,
    const float* __restrict__ bn_g, const float* __restrict__ bn_b,
    const float* __restrict__ d1w, const float* __restrict__ d1b,
    const float* __restrict__ d2w, const float* __restrict__ d2b,
    const float* __restrict__ d3w, const float* __restrict__ d3b,
    const float* __restrict__ d4w, const float* __restrict__ d4b,
    float* __restrict__ outp)
{
  __shared__ float cat[256];
  __shared__ float l1[256];
  __shared__ float l2[64];
  __shared__ float l3[16];
  const int tid = threadIdx.x;
  const int b   = blockIdx.x;
  const float bnscale = rsqrtf(1.0f + 1e-5f);

  if (tid < 253) {
    float v;
    if (tid < 84)       v = as_att[(size_t)b*84 + tid];
    else if (tid < 143) v = mrna[(size_t)b*59 + (tid - 84)];
    else {
      int j = tid - 143;
      if (j < 19)       v = f_gibbs[b*19 + j];
      else if (j < 20)  v = f_pssm[b];
      else if (j < 21)  v = f_gcs[b];
      else if (j < 23)  v = f_ssp[b*2 + (j-21)];
      else if (j < 25)  v = f_sse[b*2 + (j-23)];
      else if (j < 89)  v = f_tri[b*64 + (j-25)];
      else if (j < 105) v = f_di[b*16 + (j-89)];
      else if (j < 109) v = f_sgl[b*4 + (j-105)];
      else              v = f_gc[b];
    }
    cat[tid] = v * bnscale * bn_g[tid] + bn_b[tid];
  }
  __syncthreads();

  {
    float a = d1b[tid];
    const float* w = d1w + (size_t)tid * 253;
    for (int j = 0; j < 253; ++j) a += cat[j] * w[j];
    l1[tid] = (a > 0.f) ? a : 0.01f * a;
  }
  __syncthreads();
  if (tid < 64) {
    float a = d2b[tid];
    const float* w = d2w + (size_t)tid * 256;
    for (int j = 0; j < 256; ++j) a += l1[j] * w[j];
    l2[tid] = (a > 0.f) ? a : 0.01f * a;
  }
  __syncthreads();
  if (tid < 16) {
    float a = d3b[tid];
    const float* w = d3w + tid * 64;
    for (int j = 0; j < 64; ++j) a += l2[j] * w[j];
    l3[tid] = (a > 0.f) ? a : 0.01f * a;
  }
  __syncthreads();
  if (tid == 0) {
    float a = d4b[0];
    #pragma unroll
    for (int j = 0; j < 16; ++j) a += l3[j] * d4w[j];
    outp[b] = 1.f / (1.f + __expf(-a));
  }
}

extern "C" void kernel_launch(void* const* d_in, const int* in_sizes, int n_in,
                              void* d_out, int out_size, void* d_ws, size_t ws_size,
                              hipStream_t stream) {
  const float* rnafm   = (const float*)d_in[0];
  const float* rnafm_m = (const float*)d_in[1];
  const float* f_gibbs = (const float*)d_in[2];
  const float* f_pssm  = (const float*)d_in[3];
  const float* f_gcs   = (const float*)d_in[4];
  const float* f_ssp   = (const float*)d_in[5];
  const float* f_sse   = (const float*)d_in[6];
  const float* f_tri   = (const float*)d_in[7];
  const float* f_di    = (const float*)d_in[8];
  const float* f_sgl   = (const float*)d_in[9];
  const float* f_gc    = (const float*)d_in[10];
  const float* xmap1_w = (const float*)d_in[11];
  const float* xmap1_b = (const float*)d_in[12];
  const float* e1_qw   = (const float*)d_in[13];
  const float* e1_qb   = (const float*)d_in[14];
  const float* e1_ow   = (const float*)d_in[15];
  const float* e1_ob   = (const float*)d_in[16];
  const float* e1_f1w  = (const float*)d_in[17];
  const float* e1_f1b  = (const float*)d_in[18];
  const float* e1_f2w  = (const float*)d_in[19];
  const float* e1_f2b  = (const float*)d_in[20];
  const float* e1_g1   = (const float*)d_in[21];
  const float* e1_b1   = (const float*)d_in[22];
  const float* e1_g2   = (const float*)d_in[23];
  const float* e1_b2   = (const float*)d_in[24];
  const float* ymap1_w = (const float*)d_in[25];
  const float* ymap1_b = (const float*)d_in[26];
  const float* xmap2_w = (const float*)d_in[27];
  const float* xmap2_b = (const float*)d_in[28];
  const float* e2_qw   = (const float*)d_in[29];
  const float* e2_qb   = (const float*)d_in[30];
  const float* e2_ow   = (const float*)d_in[31];
  const float* e2_ob   = (const float*)d_in[32];
  const float* e2_f1w  = (const float*)d_in[33];
  const float* e2_f1b  = (const float*)d_in[34];
  const float* e2_f2w  = (const float*)d_in[35];
  const float* e2_f2b  = (const float*)d_in[36];
  const float* e2_g1   = (const float*)d_in[37];
  const float* e2_b1   = (const float*)d_in[38];
  const float* e2_g2   = (const float*)d_in[39];
  const float* e2_b2   = (const float*)d_in[40];
  const float* ymap2_w = (const float*)d_in[41];
  const float* ymap2_b = (const float*)d_in[42];
  const float* bn_g    = (const float*)d_in[43];
  const float* bn_b    = (const float*)d_in[44];
  const float* d1w     = (const float*)d_in[45];
  const float* d1b     = (const float*)d_in[46];
  const float* d2w     = (const float*)d_in[47];
  const float* d2b     = (const float*)d_in[48];
  const float* d3w     = (const float*)d_in[49];
  const float* d3b     = (const float*)d_in[50];
  const float* d4w     = (const float*)d_in[51];
  const float* d4b     = (const float*)d_in[52];

  float* as_att = (float*)d_ws;                                  // NB*84 f32
  float* mrna   = (float*)((char*)d_ws + (size_t)NB*84*4);       // NB*59 f32
  __bf16* bfb   = (__bf16*)((char*)d_ws + 585728);               // 610304 bf16
  __bf16* xw1B  = bfb;
  __bf16* w1B1  = bfb + 10240;
  __bf16* w2B1  = bfb + 272384;
  __bf16* xw2B  = bfb + 403456;
  __bf16* w1B2  = bfb + 413696;
  __bf16* w2B2  = bfb + 544768;
  float* outp   = (float*)d_out;

  prep_kernel<<<2384, 256, 0, stream>>>(xmap1_w, e1_f1w, e1_f2w, xmap2_w, e2_f1w, e2_f2w, bfb);

  b1_kernel<<<NB, 256, 0, stream>>>(rnafm, xmap1_b,
      e1_qw, e1_qb, e1_ow, e1_ob, e1_f1b, e1_f2b,
      e1_g1, e1_b1, e1_g2, e1_b2, ymap1_w, ymap1_b,
      xw1B, w1B1, w2B1, as_att);

  b2_kernel<<<NB, 256, 0, stream>>>(rnafm_m, xmap2_b,
      e2_qw, e2_qb, e2_ow, e2_ob, e2_f1b, e2_f2b,
      e2_g1, e2_b1, e2_g2, e2_b2, ymap2_w, ymap2_b,
      xw2B, w1B2, w2B2, mrna);

  mlp_kernel<<<NB, 256, 0, stream>>>(as_att, mrna,
      f_gibbs, f_pssm, f_gcs, f_ssp, f_sse, f_tri, f_di, f_sgl, f_gc,
      bn_g, bn_b, d1w, d1b, d2w, d2b, d3w, d3b, d4w, d4b, outp);
}